// Round 1
// baseline (89591.705 us; speedup 1.0000x reference)
//
#include <hip/hip_runtime.h>
#include <hip/hip_bf16.h>

#define Bn 64
#define Nn 1024
#define Mn 1024
#define I2n 256
#define H2n 256
#define GSTRIDE_F 5120
// scale = 2*log2(e): exp2(scale*x) = exp(2x)
#define KSCALE 2.8853900817779268f

__device__ __forceinline__ float bf2f(unsigned short u) {
    return __uint_as_float(((unsigned int)u) << 16);
}
__device__ __forceinline__ unsigned short f2bf(float f) {
    unsigned int u = __float_as_uint(f);
    u += 0x7FFFu + ((u >> 16) & 1u);
    return (unsigned short)(u >> 16);
}
__device__ __forceinline__ float rcp_fast(float x) {
#if __has_builtin(__builtin_amdgcn_rcpf)
    return __builtin_amdgcn_rcpf(x);
#else
    return 1.0f / x;
#endif
}
__device__ __forceinline__ float exp2_fast(float x) {
#if __has_builtin(__builtin_amdgcn_exp2f)
    return __builtin_amdgcn_exp2f(x);
#else
    return exp2f(x);
#endif
}
__device__ __forceinline__ float wsum(float x) {
#pragma unroll
    for (int m = 32; m > 0; m >>= 1) x += __shfl_xor(x, m, 64);
    return x;
}
__device__ __forceinline__ float wmax(float x) {
#pragma unroll
    for (int m = 32; m > 0; m >>= 1) x = fmaxf(x, __shfl_xor(x, m, 64));
    return x;
}

// -------- precompute: out[r,h] = scale * sum_i U[r,i]*W[h,i], bf16 out --------
__global__ __launch_bounds__(256)
void gemm_rw_bf16(const float* __restrict__ U, const float* __restrict__ W,
                  unsigned short* __restrict__ out, float scale) {
    __shared__ unsigned short Wlds[256 * 258];
    __shared__ float uLds[4][256];
    const int tid = threadIdx.x;
    // stage W transposed (i-major) as bf16; write banks are conflict-free via 258 pad
    for (int e = 0; e < 256; ++e) {
        float w = W[e * 256 + tid];          // h=e, i=tid (coalesced)
        Wlds[tid * 258 + e] = f2bf(w);
    }
    __syncthreads();
    const size_t r0 = (size_t)blockIdx.x * 32;
    for (int rr = 0; rr < 32; rr += 4) {
#pragma unroll
        for (int k = 0; k < 4; ++k)
            uLds[k][tid] = U[(r0 + rr + k) * 256 + tid];
        __syncthreads();
        float a0 = 0.f, a1 = 0.f, a2 = 0.f, a3 = 0.f;
#pragma unroll 4
        for (int i = 0; i < 256; ++i) {
            float w = bf2f(Wlds[i * 258 + tid]);
            a0 = fmaf(w, uLds[0][i], a0);
            a1 = fmaf(w, uLds[1][i], a1);
            a2 = fmaf(w, uLds[2][i], a2);
            a3 = fmaf(w, uLds[3][i], a3);
        }
        out[(r0 + rr + 0) * 256 + tid] = f2bf(a0 * scale);
        out[(r0 + rr + 1) * 256 + tid] = f2bf(a1 * scale);
        out[(r0 + rr + 2) * 256 + tid] = f2bf(a2 * scale);
        out[(r0 + rr + 3) * 256 + tid] = f2bf(a3 * scale);
        __syncthreads();
    }
}

__global__ void cast_scale_bf16(const float* __restrict__ src,
                                unsigned short* __restrict__ dst, int n, float scale) {
    int i = blockIdx.x * blockDim.x + threadIdx.x;
    if (i < n) dst[i] = f2bf(src[i] * scale);
}

// -------- 4-block group barrier (device-scope) --------
__device__ __forceinline__ void group_barrier(unsigned int* ctr, unsigned int target,
                                              long long& budget) {
    __syncthreads();
    if (threadIdx.x == 0) {
        __threadfence();
        __hip_atomic_fetch_add(ctr, 1u, __ATOMIC_RELEASE, __HIP_MEMORY_SCOPE_AGENT);
        while (__hip_atomic_load(ctr, __ATOMIC_ACQUIRE, __HIP_MEMORY_SCOPE_AGENT) < target) {
            __builtin_amdgcn_s_sleep(1);
            if (--budget < 0) break;   // fail fast instead of deadlocking
        }
        __threadfence();
    }
    __syncthreads();
}

// d[h] = pn[h] + sum_j v[j]*Wv_scaled[h,j]  (wave-per-h)
__device__ __forceinline__ void compute_d(const unsigned short* __restrict__ Wvb,
                                          const float vreg[4], const float* pnLds,
                                          float* dLds, int lane, int wave) {
    for (int hh = 0; hh < 32; ++hh) {
        int h = wave * 32 + hh;
        float acc = 0.f;
#pragma unroll
        for (int u = 0; u < 4; ++u)
            acc = fmaf(bf2f(Wvb[h * 256 + 64 * u + lane]), vreg[u], acc);
        acc = wsum(acc);
        if (lane == 0) dLds[h] = acc + pnLds[h];
    }
}

__global__ __launch_bounds__(512, 1)
void scan_kernel(const float* __restrict__ up, const float* __restrict__ v0,
                 const float* __restrict__ V,
                 const float* __restrict__ b_ih, const float* __restrict__ b_hh,
                 const unsigned short* __restrict__ Wuq, const unsigned short* __restrict__ Pm,
                 const unsigned short* __restrict__ uqb, const unsigned short* __restrict__ Wvb,
                 const unsigned short* __restrict__ Wg2b, const unsigned short* __restrict__ wihb,
                 const unsigned short* __restrict__ whhb,
                 float* __restrict__ out,
                 unsigned int* __restrict__ ctrs, float* __restrict__ gdata) {
    const int tid = threadIdx.x;
    const int lane = tid & 63, wave = tid >> 6;
    const int b = blockIdx.x >> 2, q = blockIdx.x & 3;

    unsigned int* ctr = ctrs + b * 16;
    float* gb = gdata + (size_t)b * GSTRIDE_F;
    float* cpartB = gb;          // [4][256]
    float* giPB   = gb + 1024;   // [4][768]
    float* ghB    = gb + 4096;   // [768]
    float* mlsB   = gb + 4864;   // [4][2]

    __shared__ unsigned short Wg2s[64 * 512];   // this block's 64 rows of Wg[256:512,:]
    __shared__ float vLds[256], dLds[256], sLds[256], eLds[256];
    __shared__ float rLds[512], cLds[64], pnLds[256];
    __shared__ float cpLds[4][256];
    __shared__ float bihs[768], bhhs[768];
    __shared__ float red[16];

    for (int e = tid; e < 64 * 512; e += 512)
        Wg2s[e] = Wg2b[(size_t)(64 * q) * 512 + e];
    for (int e = tid; e < 768; e += 512) { bihs[e] = b_ih[e]; bhhs[e] = b_hh[e]; }
    if (tid < 256) {
        vLds[tid] = v0[b * 256 + tid];
        pnLds[tid] = bf2f(Pm[(size_t)(b * Nn) * 256 + tid]);
    }
    __syncthreads();

    float Vv2[4];
#pragma unroll
    for (int j = 0; j < 4; ++j) Vv2[j] = 2.0f * V[b * 256 + 4 * lane + j];
    const float SVv = 0.5f * wsum(Vv2[0] + Vv2[1] + Vv2[2] + Vv2[3]);

    float vreg[4];
#pragma unroll
    for (int u = 0; u < 4; ++u) vreg[u] = vLds[lane + 64 * u];

    compute_d(Wvb, vreg, pnLds, dLds, lane, wave);
    __syncthreads();
    float d4[4];
#pragma unroll
    for (int j = 0; j < 4; ++j) d4[j] = dLds[4 * lane + j];

    long long budget = (1LL << 26);

    for (int t = 0; t < Nn; ++t) {
        // ---------- phase B: s[m] for this block's m-quarter ----------
        const unsigned short* wrow =
            Wuq + ((size_t)(b * Mn + 256 * q + wave * 32) * 256) + 4 * lane;
        for (int mm = 0; mm < 32; ++mm) {
            ushort4 w4 = *(const ushort4*)wrow;
            float r0 = rcp_fast(1.f + exp2_fast(bf2f(w4.x) + d4[0]));
            float r1 = rcp_fast(1.f + exp2_fast(bf2f(w4.y) + d4[1]));
            float r2 = rcp_fast(1.f + exp2_fast(bf2f(w4.z) + d4[2]));
            float r3 = rcp_fast(1.f + exp2_fast(bf2f(w4.w) + d4[3]));
            float acc = fmaf(Vv2[3], r3, fmaf(Vv2[2], r2, fmaf(Vv2[1], r1, Vv2[0] * r0)));
            acc = wsum(acc);
            if (lane == 0) sLds[wave * 32 + mm] = SVv - acc;
            wrow += 256;
        }
        __syncthreads();

        // ---------- local softmax over 256 m ----------
        float sv = (tid < 256) ? sLds[tid] : -3.0e38f;
        float mx = wmax(sv);
        if (lane == 0) red[wave] = mx;
        __syncthreads();
        float mloc = red[0];
#pragma unroll
        for (int w2 = 1; w2 < 8; ++w2) mloc = fmaxf(mloc, red[w2]);
        float ev = (tid < 256) ? __expf(sv - mloc) : 0.f;
        if (tid < 256) eLds[tid] = ev;
        float sm = wsum(ev);
        if (lane == 0) red[8 + wave] = sm;
        __syncthreads();
        float sumloc = red[8] + red[9] + red[10] + red[11] +
                       red[12] + red[13] + red[14] + red[15];

        // ---------- phase D: cpart[i] = sum_m e[m]*uq[b,m,i] ----------
        {
            const int i2 = (tid & 127) * 2, qm = tid >> 7;
            const unsigned short* urow =
                uqb + ((size_t)(b * Mn + 256 * q + 64 * qm) * 256) + i2;
            float a0 = 0.f, a1 = 0.f;
            for (int mm = 0; mm < 64; ++mm) {
                float e = eLds[64 * qm + mm];
                ushort2 u2 = *(const ushort2*)urow;
                a0 = fmaf(e, bf2f(u2.x), a0);
                a1 = fmaf(e, bf2f(u2.y), a1);
                urow += 256;
            }
            cpLds[qm][i2] = a0;
            cpLds[qm][i2 + 1] = a1;
        }
        __syncthreads();
        if (tid < 256)
            cpartB[q * 256 + tid] =
                cpLds[0][tid] + cpLds[1][tid] + cpLds[2][tid] + cpLds[3][tid];
        if (tid == 0) { mlsB[q * 2] = mloc; mlsB[q * 2 + 1] = sumloc; }

        group_barrier(ctr + 0, 4u * (t + 1), budget);

        // ---------- combine c, build r = [up_t, c] ----------
        if (tid < 256) {
            float m0 = mlsB[0], s0 = mlsB[1], m1 = mlsB[2], s1 = mlsB[3];
            float m2 = mlsB[4], s2 = mlsB[5], m3 = mlsB[6], s3 = mlsB[7];
            float Mg = fmaxf(fmaxf(m0, m1), fmaxf(m2, m3));
            float w0 = __expf(m0 - Mg), w1 = __expf(m1 - Mg);
            float w2 = __expf(m2 - Mg), w3 = __expf(m3 - Mg);
            float denom = s0 * w0 + s1 * w1 + s2 * w2 + s3 * w3;
            float c = cpartB[tid] * w0 + cpartB[256 + tid] * w1 +
                      cpartB[512 + tid] * w2 + cpartB[768 + tid] * w3;
            rLds[256 + tid] = c * rcp_fast(denom);
            rLds[tid] = up[((size_t)b * Nn + t) * 256 + tid];
        }
        __syncthreads();

        // ---------- E: c_[o] for this block's 64-output slice ----------
#pragma unroll
        for (int oo = 0; oo < 8; ++oo) {
            int ol = wave * 8 + oo;
            float acc = 0.f;
#pragma unroll
            for (int u = 0; u < 8; ++u)
                acc = fmaf(bf2f(Wg2s[ol * 512 + 64 * u + lane]), rLds[64 * u + lane], acc);
            acc = wsum(acc);
            if (lane == 0) {
                float g = rcp_fast(1.f + __expf(-acc));
                cLds[ol] = g * rLds[256 + 64 * q + ol];
            }
        }
        __syncthreads();

        // ---------- F: gi partial over this block's 64 k's ----------
        for (int j = tid; j < 768; j += 512) {
            const unsigned short* wr = wihb + (size_t)j * 256 + 64 * q;
            float acc = 0.f;
#pragma unroll
            for (int kk = 0; kk < 16; ++kk) {
                ushort4 w4 = *(const ushort4*)(wr + 4 * kk);
                acc = fmaf(bf2f(w4.x), cLds[4 * kk + 0], acc);
                acc = fmaf(bf2f(w4.y), cLds[4 * kk + 1], acc);
                acc = fmaf(bf2f(w4.z), cLds[4 * kk + 2], acc);
                acc = fmaf(bf2f(w4.w), cLds[4 * kk + 3], acc);
            }
            giPB[q * 768 + j] = acc;
        }
        // ---------- F: gh for this block's 192 output rows ----------
        if (tid < 192) {
            int part = tid >> 6, l = tid & 63;
            int j = part * 256 + 64 * q + l;
            const unsigned short* wr = whhb + (size_t)j * 256;
            float acc = 0.f;
#pragma unroll 4
            for (int kk = 0; kk < 64; ++kk) {
                ushort4 w4 = *(const ushort4*)(wr + 4 * kk);
                acc = fmaf(bf2f(w4.x), vLds[4 * kk + 0], acc);
                acc = fmaf(bf2f(w4.y), vLds[4 * kk + 1], acc);
                acc = fmaf(bf2f(w4.z), vLds[4 * kk + 2], acc);
                acc = fmaf(bf2f(w4.w), vLds[4 * kk + 3], acc);
            }
            ghB[j] = acc;
        }
        if (t + 1 < Nn && tid < 256)
            pnLds[tid] = bf2f(Pm[((size_t)b * Nn + t + 1) * 256 + tid]);

        group_barrier(ctr + 1, 4u * (t + 1), budget);

        // ---------- gates (redundant per block) ----------
        if (tid < 256) {
            int h = tid;
            float gir = giPB[h] + giPB[768 + h] + giPB[1536 + h] + giPB[2304 + h];
            float giz = giPB[256 + h] + giPB[768 + 256 + h] +
                        giPB[1536 + 256 + h] + giPB[2304 + 256 + h];
            float gin = giPB[512 + h] + giPB[768 + 512 + h] +
                        giPB[1536 + 512 + h] + giPB[2304 + 512 + h];
            float ghr = ghB[h] + bhhs[h];
            float ghz = ghB[256 + h] + bhhs[256 + h];
            float ghn = ghB[512 + h] + bhhs[512 + h];
            float rr = rcp_fast(1.f + __expf(-(gir + bihs[h] + ghr)));
            float zz = rcp_fast(1.f + __expf(-(giz + bihs[256 + h] + ghz)));
            float narg = gin + bihs[512 + h] + rr * ghn;
            float en = __expf(2.f * narg);
            float nn = 1.f - 2.f * rcp_fast(1.f + en);
            float vnew = (1.f - zz) * nn + zz * vLds[h];
            if ((h >> 6) == q) out[((size_t)t * Bn + b) * 256 + h] = vnew;
            vLds[h] = vnew;
        }
        __syncthreads();
#pragma unroll
        for (int u = 0; u < 4; ++u) vreg[u] = vLds[lane + 64 * u];
        if (t + 1 < Nn) {
            compute_d(Wvb, vreg, pnLds, dLds, lane, wave);
            __syncthreads();
#pragma unroll
            for (int j = 0; j < 4; ++j) d4[j] = dLds[4 * lane + j];
        }
    }
}

extern "C" void kernel_launch(void* const* d_in, const int* in_sizes, int n_in,
                              void* d_out, int out_size, void* d_ws, size_t ws_size,
                              hipStream_t stream) {
    const float* up   = (const float*)d_in[0];
    const float* uq   = (const float*)d_in[1];
    const float* v0   = (const float*)d_in[2];
    const float* V    = (const float*)d_in[3];
    const float* Wp   = (const float*)d_in[4];
    const float* Wq   = (const float*)d_in[5];
    const float* Wv   = (const float*)d_in[6];
    const float* Wg   = (const float*)d_in[7];
    const float* w_ih = (const float*)d_in[8];
    const float* w_hh = (const float*)d_in[9];
    const float* b_ih = (const float*)d_in[10];
    const float* b_hh = (const float*)d_in[11];
    float* out = (float*)d_out;

    char* ws = (char*)d_ws;
    unsigned int* ctrs = (unsigned int*)ws;                 // 4096 B (64 groups x 16 uints)
    float* gdata = (float*)(ws + 4096);                     // 64 x 5120 floats
    unsigned short* WuqB = (unsigned short*)(ws + 0x180000);
    unsigned short* PB   = WuqB + (size_t)Bn * Mn * 256;    // 16,777,216 each
    unsigned short* uqB  = PB + (size_t)Bn * Nn * 256;
    unsigned short* WvB  = uqB + (size_t)Bn * Mn * 256;
    unsigned short* Wg2B = WvB + 65536;
    unsigned short* wihB = Wg2B + 131072;
    unsigned short* whhB = wihB + 196608;

    hipMemsetAsync(ctrs, 0, 4096, stream);

    // precompute Wuq = K * uq@Wq^T ; P = K * up@Wp^T  (bf16)
    hipLaunchKernelGGL(gemm_rw_bf16, dim3(2048), dim3(256), 0, stream, uq, Wq, WuqB, KSCALE);
    hipLaunchKernelGGL(gemm_rw_bf16, dim3(2048), dim3(256), 0, stream, up, Wp, PB, KSCALE);
    // casts
    hipLaunchKernelGGL(cast_scale_bf16, dim3(65536), dim3(256), 0, stream, uq, uqB, 16777216, 1.0f);
    hipLaunchKernelGGL(cast_scale_bf16, dim3(256), dim3(256), 0, stream, Wv, WvB, 65536, KSCALE);
    hipLaunchKernelGGL(cast_scale_bf16, dim3(512), dim3(256), 0, stream, Wg + 131072, Wg2B, 131072, 1.0f);
    hipLaunchKernelGGL(cast_scale_bf16, dim3(768), dim3(256), 0, stream, w_ih, wihB, 196608, 1.0f);
    hipLaunchKernelGGL(cast_scale_bf16, dim3(768), dim3(256), 0, stream, w_hh, whhB, 196608, 1.0f);

    hipLaunchKernelGGL(scan_kernel, dim3(256), dim3(512), 0, stream,
                       up, v0, V, b_ih, b_hh,
                       WuqB, PB, uqB, WvB, Wg2B, wihB, whhB,
                       out, ctrs, gdata);
}

// Round 2
// 59248.615 us; speedup vs baseline: 1.5121x; 1.5121x over previous
//
#include <hip/hip_runtime.h>

#define Bn 64
#define Nn 1024
#define Mn 1024
#define GSTR 7680
// scale = 2*log2(e): exp2(scale*x) = exp(2x)
#define KSCALE 2.8853900817779268f

typedef unsigned short u16;

__device__ __forceinline__ float us2f(u16 u) {
    _Float16 h = __builtin_bit_cast(_Float16, u);
    return (float)h;
}
__device__ __forceinline__ u16 f2h(float f) {
    _Float16 h = (_Float16)f;
    return __builtin_bit_cast(u16, h);
}
__device__ __forceinline__ float rcp_fast(float x) {
#if __has_builtin(__builtin_amdgcn_rcpf)
    return __builtin_amdgcn_rcpf(x);
#else
    return 1.0f / x;
#endif
}
__device__ __forceinline__ float exp2_fast(float x) {
#if __has_builtin(__builtin_amdgcn_exp2f)
    return __builtin_amdgcn_exp2f(x);
#else
    return exp2f(x);
#endif
}
__device__ __forceinline__ float wsum(float x) {
#pragma unroll
    for (int m = 32; m > 0; m >>= 1) x += __shfl_xor(x, m, 64);
    return x;
}
__device__ __forceinline__ float wmax(float x) {
#pragma unroll
    for (int m = 32; m > 0; m >>= 1) x = fmaxf(x, __shfl_xor(x, m, 64));
    return x;
}

// ---------- precompute: 32-row tile of  out = scale * U @ W^T  (f16 out) ----------
// transposed==0: outN[row][h]   (row-major, for P)
// transposed==1: outT[b][h][m]  (h-major, for WuqT)
__global__ __launch_bounds__(256)
void gemm_f16(const float* __restrict__ U, const float* __restrict__ W,
              u16* __restrict__ outN, u16* __restrict__ outT,
              int transposed, float scale) {
    __shared__ float WL[256 * 33];
    __shared__ float uL[32 * 33];
    const int tid = threadIdx.x;
    const size_t row0 = (size_t)blockIdx.x * 32;
    float acc[32];
#pragma unroll
    for (int m = 0; m < 32; ++m) acc[m] = 0.f;
    for (int ic = 0; ic < 8; ++ic) {
        __syncthreads();
        for (int e = tid; e < 8192; e += 256) {
            int h = e >> 5, ii = e & 31;
            WL[h * 33 + ii] = W[h * 256 + ic * 32 + ii];
        }
        for (int e = tid; e < 1024; e += 256) {
            int r = e >> 5, ii = e & 31;
            uL[r * 33 + ii] = U[(row0 + r) * 256 + ic * 32 + ii];
        }
        __syncthreads();
#pragma unroll 4
        for (int ii = 0; ii < 32; ++ii) {
            float w = WL[tid * 33 + ii];
#pragma unroll
            for (int m = 0; m < 32; ++m)
                acc[m] = fmaf(w, uL[m * 33 + ii], acc[m]);
        }
    }
    if (!transposed) {
#pragma unroll
        for (int m = 0; m < 32; ++m)
            outN[(row0 + m) * 256 + tid] = f2h(scale * acc[m]);
    } else {
        __syncthreads();
#pragma unroll
        for (int m = 0; m < 32; ++m) WL[tid * 33 + m] = acc[m];
        __syncthreads();
        const size_t batch = row0 >> 10;
        const int m0 = (int)(row0 & 1023);
        for (int e = tid; e < 8192; e += 256) {
            int h = e >> 5, mm = e & 31;
            outT[(batch * 256 + h) * 1024 + m0 + mm] = f2h(scale * WL[h * 33 + mm]);
        }
    }
}

__global__ void cast_f16k(const float* __restrict__ src, u16* __restrict__ dst, int n) {
    int i = blockIdx.x * blockDim.x + threadIdx.x;
    if (i < n) dst[i] = f2h(src[i]);
}
// dst[c*R + r] = scale * src[r*C + c]
__global__ void transpose_f16k(const float* __restrict__ src, u16* __restrict__ dst,
                               int R, int C, float scale) {
    int o = blockIdx.x * blockDim.x + threadIdx.x;
    if (o >= R * C) return;
    int c = o / R, r = o - c * R;
    dst[o] = f2h(scale * src[r * C + c]);
}
__global__ void transpose_f32k(const float* __restrict__ src, float* __restrict__ dst,
                               int R, int C) {
    int o = blockIdx.x * blockDim.x + threadIdx.x;
    if (o >= R * C) return;
    int c = o / R, r = o - c * R;
    dst[o] = src[r * C + c];
}

// -------- 4-block group barrier (device-scope), unchanged from passing version --------
__device__ __forceinline__ void group_barrier(unsigned int* ctr, unsigned int target,
                                              long long& budget) {
    __syncthreads();
    if (threadIdx.x == 0) {
        __threadfence();
        __hip_atomic_fetch_add(ctr, 1u, __ATOMIC_RELEASE, __HIP_MEMORY_SCOPE_AGENT);
        while (__hip_atomic_load(ctr, __ATOMIC_ACQUIRE, __HIP_MEMORY_SCOPE_AGENT) < target) {
            __builtin_amdgcn_s_sleep(1);
            if (--budget < 0) break;   // fail fast instead of deadlocking
        }
        __threadfence();
    }
    __syncthreads();
}

__global__ __launch_bounds__(1024, 4)
void scan_kernel(const float* __restrict__ up, const float* __restrict__ v0,
                 const float* __restrict__ V, const float* __restrict__ b_ih,
                 const float* __restrict__ b_hh,
                 const u16* __restrict__ WuqT, const u16* __restrict__ Pm,
                 const u16* __restrict__ uqH, const u16* __restrict__ WvT,
                 const u16* __restrict__ wihT, const u16* __restrict__ whhT,
                 const float* __restrict__ Wg2T,
                 float* __restrict__ out, unsigned int* __restrict__ ctrs,
                 float* __restrict__ gdata) {
    const int tid = threadIdx.x;
    const int bid = blockIdx.x;
    // co-locate a batch's 4 blocks on one XCD (bid%8 = XCD under round-robin dispatch)
    const int x = bid & 7, q = (bid >> 3) & 3, bhi = bid >> 5;
    const int b = (bhi << 3) | x;

    unsigned int* ctr = ctrs + b * 16;
    float* gb = gdata + (size_t)b * GSTR;
    float* cpartB = gb;          // [4][256]
    float* mlsB   = gb + 1024;   // [8]
    float* giPB   = gb + 1032;   // [4][768]
    float* ghPB   = gb + 4104;   // [4][768]

    __shared__ float Wg2s[512 * 64];     // this block's o-slice of Wg2^T, f32
    __shared__ float scratch[8 * 256];
    __shared__ float VvLds[256], vLds[256], dLds[256], eLds[256], pnLds[256];
    __shared__ float rLds[512];
    __shared__ float cLds[64];
    __shared__ float bihs[768], bhhs[768];
    __shared__ float red[32];
    __shared__ float svv_sh;

    for (int e = tid; e < 512 * 64; e += 1024)
        Wg2s[e] = Wg2T[(e >> 6) * 256 + 64 * q + (e & 63)];
    if (tid < 768) { bihs[tid] = b_ih[tid]; bhhs[tid] = b_hh[tid]; }
    if (tid < 256) {
        vLds[tid]  = v0[b * 256 + tid];
        VvLds[tid] = 2.0f * V[b * 256 + tid];
        pnLds[tid] = us2f(Pm[(size_t)b * Nn * 256 + tid]);   // t=0 row (K-scaled)
    }
    __syncthreads();
    if (tid < 256) {
        float s = wsum(VvLds[tid]);
        if ((tid & 63) == 0) red[tid >> 6] = s;
    }
    {   // initial d partials: d = pn + Wv@v  (thread-private over j-chunk)
        const int h = tid & 255, jc = tid >> 8;
        float acc = 0.f;
        const u16* wv = WvT + (jc * 64) * 256 + h;
#pragma unroll 4
        for (int jj = 0; jj < 64; ++jj)
            acc = fmaf(us2f(wv[jj * 256]), vLds[jc * 64 + jj], acc);
        scratch[jc * 256 + h] = acc;
    }
    __syncthreads();
    if (tid == 0) svv_sh = 0.5f * (red[0] + red[1] + red[2] + red[3]);
    if (tid < 256)
        dLds[tid] = pnLds[tid] + scratch[tid] + scratch[256 + tid] +
                    scratch[512 + tid] + scratch[768 + tid];
    __syncthreads();
    const float SVv = svv_sh;

    const u16* WuqB_b = WuqT + (size_t)b * 256 * 1024;   // [h][m]
    const u16* uq_b   = uqH + (size_t)b * 1024 * 256;    // [m][i]
    const float* up_b = up + (size_t)b * Nn * 256;

    long long budget = 1LL << 26;
    float mloc, sumloc;

    for (int t = 0; t < Nn; ++t) {
        // ---- B: score partials, thread-private over h-chunk, 2 m's per thread ----
        {
            const int ml2 = (tid & 127) * 2;
            const int hc  = tid >> 7;                    // 0..7
            float a0 = 0.f, a1 = 0.f;
            const u16* wp = WuqB_b + (size_t)(hc * 32) * 1024 + q * 256 + ml2;
#pragma unroll 4
            for (int hh = 0; hh < 32; ++hh) {
                const int h = hc * 32 + hh;
                const float dv = dLds[h];                // wave-uniform broadcast
                const float vv = VvLds[h];
                unsigned int w2 = *(const unsigned int*)wp;   // two f16 (m, m+1)
                float w0 = us2f((u16)(w2 & 0xffffu));
                float w1 = us2f((u16)(w2 >> 16));
                a0 = fmaf(vv, rcp_fast(1.f + exp2_fast(w0 + dv)), a0);
                a1 = fmaf(vv, rcp_fast(1.f + exp2_fast(w1 + dv)), a1);
                wp += 1024;
            }
            ((float2*)scratch)[hc * 128 + (tid & 127)] = make_float2(a0, a1);
        }
        __syncthreads();

        // ---- local softmax over this block's 256 m (redundant x4 copies) ----
        {
            const int m = tid & 255;
            float sv = SVv;
#pragma unroll
            for (int c2 = 0; c2 < 8; ++c2) sv -= scratch[c2 * 256 + m];
            float mx = wmax(sv);
            if ((tid & 63) == 0) red[tid >> 6] = mx;
            __syncthreads();
            mloc = red[0];
#pragma unroll
            for (int w2 = 1; w2 < 16; ++w2) mloc = fmaxf(mloc, red[w2]);
            float ev = __expf(sv - mloc);
            if (tid < 256) eLds[m] = ev;
            float sm = wsum(ev);
            if ((tid & 63) == 0) red[16 + (tid >> 6)] = sm;
            __syncthreads();
            sumloc = red[16] + red[17] + red[18] + red[19];
        }

        // ---- D: cpart[i] = sum_m e[m]*uq[m,i], thread-private over m-chunk ----
        {
            const int i = tid & 255, ms = tid >> 8;
            const u16* uprow = uq_b + (size_t)(q * 256 + ms * 64) * 256 + i;
            float acc = 0.f;
#pragma unroll 4
            for (int mm = 0; mm < 64; ++mm) {
                acc = fmaf(eLds[ms * 64 + mm], us2f(*uprow), acc);
                uprow += 256;
            }
            scratch[ms * 256 + i] = acc;
        }
        __syncthreads();
        if (tid < 256)
            cpartB[q * 256 + tid] = scratch[tid] + scratch[256 + tid] +
                                    scratch[512 + tid] + scratch[768 + tid];
        if (tid == 0) { mlsB[2 * q] = mloc; mlsB[2 * q + 1] = sumloc; }

        group_barrier(ctr + 0, 4u * (unsigned)(t + 1), budget);

        // ---- combine softmax across blocks; r = [up_t, c] ----
        if (tid < 256) {
            float m0 = mlsB[0], s0 = mlsB[1], m1 = mlsB[2], s1 = mlsB[3];
            float m2 = mlsB[4], s2 = mlsB[5], m3 = mlsB[6], s3 = mlsB[7];
            float Mg = fmaxf(fmaxf(m0, m1), fmaxf(m2, m3));
            float w0 = __expf(m0 - Mg), w1 = __expf(m1 - Mg);
            float w2 = __expf(m2 - Mg), w3 = __expf(m3 - Mg);
            float denom = s0 * w0 + s1 * w1 + s2 * w2 + s3 * w3;
            float c = cpartB[tid] * w0 + cpartB[256 + tid] * w1 +
                      cpartB[512 + tid] * w2 + cpartB[768 + tid] * w3;
            rLds[256 + tid] = c * rcp_fast(denom);
            rLds[tid] = up_b[(size_t)t * 256 + tid];
        }
        __syncthreads();

        // ---- E: g = sigmoid(Wg2 @ r) for this block's 64 outputs ----
        {
            const int o = tid & 63, ks = tid >> 6;
            const float* wg = Wg2s + (ks * 32) * 64 + o;
            float acc = 0.f;
#pragma unroll 8
            for (int kk = 0; kk < 32; ++kk)
                acc = fmaf(wg[kk * 64], rLds[ks * 32 + kk], acc);
            scratch[ks * 64 + o] = acc;
        }
        __syncthreads();
        if (tid < 64) {
            float acc = 0.f;
#pragma unroll
            for (int c2 = 0; c2 < 16; ++c2) acc += scratch[c2 * 64 + tid];
            float g = rcp_fast(1.f + __expf(-acc));
            cLds[tid] = g * rLds[256 + 64 * q + tid];
        }
        __syncthreads();

        // ---- F: gi/gh partials over this block's 64-k slice ----
        if (tid < 768) {
            const u16* wi = wihT + (64 * q) * 768 + tid;
            const u16* wh = whhT + (64 * q) * 768 + tid;
            float gi = 0.f, gh = 0.f;
#pragma unroll 4
            for (int kk = 0; kk < 64; ++kk) {
                gi = fmaf(us2f(wi[kk * 768]), cLds[kk], gi);
                gh = fmaf(us2f(wh[kk * 768]), vLds[64 * q + kk], gh);
            }
            giPB[q * 768 + tid] = gi;
            ghPB[q * 768 + tid] = gh;
        } else if (t + 1 < Nn) {
            const int h = tid - 768;
            pnLds[h] = us2f(Pm[((size_t)b * Nn + t + 1) * 256 + h]);
        }

        group_barrier(ctr + 1, 4u * (unsigned)(t + 1), budget);

        // ---- gates (redundant per block) + v update ----
        if (tid < 256) {
            const int h = tid;
            float gir = giPB[h] + giPB[768 + h] + giPB[1536 + h] + giPB[2304 + h] + bihs[h];
            float giz = giPB[256 + h] + giPB[1024 + h] + giPB[1792 + h] + giPB[2560 + h] + bihs[256 + h];
            float gin = giPB[512 + h] + giPB[1280 + h] + giPB[2048 + h] + giPB[2816 + h] + bihs[512 + h];
            float ghr = ghPB[h] + ghPB[768 + h] + ghPB[1536 + h] + ghPB[2304 + h] + bhhs[h];
            float ghz = ghPB[256 + h] + ghPB[1024 + h] + ghPB[1792 + h] + ghPB[2560 + h] + bhhs[256 + h];
            float ghn = ghPB[512 + h] + ghPB[1280 + h] + ghPB[2048 + h] + ghPB[2816 + h] + bhhs[512 + h];
            float rr = rcp_fast(1.f + __expf(-(gir + ghr)));
            float zz = rcp_fast(1.f + __expf(-(giz + ghz)));
            float narg = gin + rr * ghn;
            float nn = 1.f - 2.f * rcp_fast(1.f + __expf(2.f * narg));
            float vnew = (1.f - zz) * nn + zz * vLds[h];
            if ((h >> 6) == q) out[((size_t)t * Bn + b) * 256 + h] = vnew;
            vLds[h] = vnew;
        }
        __syncthreads();
        // ---- d for t+1 ----
        if (t + 1 < Nn) {
            const int h = tid & 255, jc = tid >> 8;
            float acc = 0.f;
            const u16* wv = WvT + (jc * 64) * 256 + h;
#pragma unroll 4
            for (int jj = 0; jj < 64; ++jj)
                acc = fmaf(us2f(wv[jj * 256]), vLds[jc * 64 + jj], acc);
            scratch[jc * 256 + h] = acc;
            __syncthreads();
            if (tid < 256)
                dLds[h] = pnLds[h] + scratch[h] + scratch[256 + h] +
                          scratch[512 + h] + scratch[768 + h];
            __syncthreads();
        }
    }
}

extern "C" void kernel_launch(void* const* d_in, const int* in_sizes, int n_in,
                              void* d_out, int out_size, void* d_ws, size_t ws_size,
                              hipStream_t stream) {
    const float* up   = (const float*)d_in[0];
    const float* uq   = (const float*)d_in[1];
    const float* v0   = (const float*)d_in[2];
    const float* V    = (const float*)d_in[3];
    const float* Wp   = (const float*)d_in[4];
    const float* Wq   = (const float*)d_in[5];
    const float* Wv   = (const float*)d_in[6];
    const float* Wg   = (const float*)d_in[7];
    const float* w_ih = (const float*)d_in[8];
    const float* w_hh = (const float*)d_in[9];
    const float* b_ih = (const float*)d_in[10];
    const float* b_hh = (const float*)d_in[11];
    float* out = (float*)d_out;

    char* ws = (char*)d_ws;
    unsigned int* ctrs = (unsigned int*)ws;                 // 4 KB
    float* gdata = (float*)(ws + 4096);                     // 64 * 7680 f32 ≈ 1.9 MB
    u16* WuqT = (u16*)(ws + (size_t)(2u << 20));            // [64][256][1024] f16
    u16* Pm   = WuqT + (size_t)Bn * 256 * 1024;             // [64][1024][256] f16
    u16* uqH  = Pm + (size_t)Bn * Nn * 256;                 // [64][1024][256] f16
    u16* WvT  = uqH + (size_t)Bn * Mn * 256;                // [256 j][256 h] f16
    u16* wihT = WvT + 65536;                                // [256 k][768 j] f16
    u16* whhT = wihT + 196608;                              // [256 k][768 j] f16
    float* Wg2T = (float*)(whhT + 196608);                  // [512 k][256 o] f32

    hipMemsetAsync(ctrs, 0, 4096, stream);

    hipLaunchKernelGGL(gemm_f16, dim3(2048), dim3(256), 0, stream,
                       uq, Wq, (u16*)nullptr, WuqT, 1, KSCALE);
    hipLaunchKernelGGL(gemm_f16, dim3(2048), dim3(256), 0, stream,
                       up, Wp, Pm, (u16*)nullptr, 0, KSCALE);
    hipLaunchKernelGGL(cast_f16k, dim3(65536), dim3(256), 0, stream, uq, uqH, 16777216);
    hipLaunchKernelGGL(transpose_f16k, dim3(256), dim3(256), 0, stream, Wv, WvT, 256, 256, KSCALE);
    hipLaunchKernelGGL(transpose_f16k, dim3(768), dim3(256), 0, stream, w_ih, wihT, 768, 256, 1.0f);
    hipLaunchKernelGGL(transpose_f16k, dim3(768), dim3(256), 0, stream, w_hh, whhT, 768, 256, 1.0f);
    hipLaunchKernelGGL(transpose_f32k, dim3(512), dim3(256), 0, stream, Wg + 256 * 512, Wg2T, 256, 512);

    hipLaunchKernelGGL(scan_kernel, dim3(256), dim3(1024), 0, stream,
                       up, v0, V, b_ih, b_hh,
                       WuqT, Pm, uqH, WvT, wihT, whhT, Wg2T,
                       out, ctrs, gdata);
}